// Round 10
// baseline (595.745 us; speedup 1.0000x reference)
//
#include <hip/hip_runtime.h>
#include <hip/hip_bf16.h>

typedef unsigned short ushort_t;
typedef unsigned int uint_t;

#define KL 1024
#define IL 8192
#define DIMV 128
#define NS 16
#define NB 258               // 32-col blocks per strip (258*32 = 8256 skewed steps)
#define NR 267               // streamer rounds (1 block/strip/round)
#define SSH (8256*64)        // ushorts per strip of c_h (fp16, pair-packed)
#define GATE 416             // cross-wg start cushion (cols)
#define BIGF 0x3fffffff
#define INF __builtin_inff()

// LDS flag indices
#define CF 0   // cflag[k]: highest c block staged for strip k (streamer -> DP)
#define PF 4   // pflag[k]: highest block completed by DP wave k
#define GF 8   // gflag: highest feed block staged (feeder -> wave0)
#define EF 9   // eflag: highest ring block consumed by exporter (exporter -> wave3)

typedef __attribute__((ext_vector_type(8))) short v8s;
typedef __attribute__((ext_vector_type(4))) float v4f;

// ---------------- kernel 1: squared row norms + zero flags ----------------
__global__ __launch_bounds__(256) void knorms(
    const float* __restrict__ kern, const float* __restrict__ xx,
    float* __restrict__ x2, float* __restrict__ k2, int* __restrict__ flags) {
  if (blockIdx.x == 0 && threadIdx.x < NS) flags[threadIdx.x] = 0;
  const int lane = threadIdx.x & 63;
  const int row = blockIdx.x * 4 + (threadIdx.x >> 6);
  const float* src;
  float* dst;
  if (row < IL) { src = xx + (size_t)row * DIMV; dst = x2 + row; }
  else          { src = kern + (size_t)(row - IL) * DIMV; dst = k2 + (row - IL); }
  float2 v = *(const float2*)(src + lane * 2);
  float ss = v.x * v.x + v.y * v.y;
  #pragma unroll
  for (int off = 32; off > 0; off >>= 1) ss += __shfl_down(ss, off, 64);
  if (lane == 0) *dst = ss;
}

// ---------------- kernel 2: MFMA bf16 GEMM -> c (fp16), diagonal-skew-stored ----
__device__ __forceinline__ v8s pack_bf16x8(float4 a, float4 b) {
  union { unsigned int u[4]; v8s v; } r;
  union { __hip_bfloat162 h; unsigned int u; } t;
  t.h = __float22bfloat162_rn(make_float2(a.x, a.y)); r.u[0] = t.u;
  t.h = __float22bfloat162_rn(make_float2(a.z, a.w)); r.u[1] = t.u;
  t.h = __float22bfloat162_rn(make_float2(b.x, b.y)); r.u[2] = t.u;
  t.h = __float22bfloat162_rn(make_float2(b.z, b.w)); r.u[3] = t.u;
  return r.v;
}

__global__ __launch_bounds__(256) void kgemm(
    const float* __restrict__ kern, const float* __restrict__ xx,
    const float* __restrict__ x2, const float* __restrict__ k2,
    ushort_t* __restrict__ c_h) {
  __shared__ float ctile[64 * 64];
  const int T = threadIdx.x;
  const int w = T >> 6;
  const int lane = T & 63;
  const int lo = lane & 15;
  const int hi = lane >> 4;
  const int i0 = blockIdx.x * 64;
  const int s  = blockIdx.y;
  const int kr0 = s * 64;

  v4f acc[4] = {};
  #pragma unroll
  for (int ks = 0; ks < 4; ks++) {
    const int k = ks * 32 + hi * 8;
    const float* bp = xx + (size_t)(i0 + w * 16 + lo) * DIMV + k;
    v8s bf = pack_bf16x8(*(const float4*)bp, *(const float4*)(bp + 4));
    #pragma unroll
    for (int rt = 0; rt < 4; rt++) {
      const float* ap = kern + (size_t)(kr0 + rt * 16 + lo) * DIMV + k;
      v8s af = pack_bf16x8(*(const float4*)ap, *(const float4*)(ap + 4));
      acc[rt] = __builtin_amdgcn_mfma_f32_16x16x32_bf16(af, bf, acc[rt], 0, 0, 0);
    }
  }
  const float x2v = x2[i0 + w * 16 + lo];
  const int n_local = w * 16 + lo;
  #pragma unroll
  for (int rt = 0; rt < 4; rt++) {
    float4 k2f = *(const float4*)&k2[kr0 + rt * 16 + hi * 4];
    #pragma unroll
    for (int q = 0; q < 4; q++) {
      const int m_local = rt * 16 + hi * 4 + q;
      float cval = fmaxf((&k2f.x)[q] + x2v - 2.f * acc[rt][q], 0.f);
      ctile[n_local * 64 + ((m_local + 2 * n_local) & 63)] = cval;
    }
  }
  __syncthreads();
  _Float16* ob = (_Float16*)(c_h + (size_t)s * SSH);
  #pragma unroll
  for (int q = 0; q < 32; q++) {
    int tt = w + q * 4;
    int di = tt - lane;
    if (tt <= 126 && di >= 0 && di < 64) {
      int t = i0 + tt;
      ob[((size_t)(t >> 1) * 64 + lane) * 2 + (t & 1)] =
          (_Float16)ctile[di * 64 + ((lane + 2 * di) & 63)];
    }
  }
}

// ---------------- kernel 3: barrier-free dataflow, 7 waves ----------------
__device__ __forceinline__ float dpp_wave_shr1(float oldv, float src) {
  return __int_as_float(__builtin_amdgcn_update_dpp(
      __float_as_int(oldv), __float_as_int(src), 0x138, 0xF, 0xF, false));
}
__device__ __forceinline__ float dpp_wave_rol1(float src) {
  return __int_as_float(__builtin_amdgcn_update_dpp(
      __float_as_int(src), __float_as_int(src), 0x134, 0xF, 0xF, false));
}
__device__ __forceinline__ float dpp_wave_shl1(float oldv, float src) {
  return __int_as_float(__builtin_amdgcn_update_dpp(
      __float_as_int(oldv), __float_as_int(src), 0x130, 0xF, 0xF, false));
}

__device__ __forceinline__ int lds_poll_ge(int* p, int need, int cached) {
  if (cached >= need) return cached;
  int f;
  do { f = __hip_atomic_load(p, __ATOMIC_RELAXED, __HIP_MEMORY_SCOPE_WORKGROUP); } while (f < need);
  return f;
}

__global__ __launch_bounds__(448) void kdp(
    const ushort_t* __restrict__ c_h, float* __restrict__ bound,
    int* __restrict__ flags, float* __restrict__ out) {
  __shared__ uint_t cbuf[13 * 1024];   // 4 strips x 3 slots x 1024 + scratch slot 12 (52 KB)
  __shared__ float ring[4 * 4 * 32];   // DP wave k ring -> consumer k+1 / exporter
  __shared__ float feedb[4 * 32];      // feeder -> wave0
  __shared__ int flg[16];
  const int g = blockIdx.x;
  const int wv = threadIdx.x >> 6;     // 0..3 DP, 4 streamer, 5 feeder, 6 exporter
  const int lane = threadIdx.x & 63;
  const int sb = g * 4;

  if (threadIdx.x < 16) {
    int v = -1;
    if (threadIdx.x == GF && g == 0) v = BIGF;
    if (threadIdx.x == EF && g == 3) v = BIGF;
    flg[threadIdx.x] = v;
  }
  if (wv == 1) { feedb[lane] = INF; feedb[64 + lane] = INF; }
  __syncthreads();   // the only barrier

  if (wv < 4) {
    // ================= DP wave k: pure LDS + DPP =================
    const int k = wv;
    float Dcur = (g == 0 && k == 0 && lane == 0) ? 0.f : INF;
    float Dul = INF, Bout = INF;
    int fc = -1, fp = -1;
    int fe = (g == 3 && k == 3) ? BIGF : -1;
    int s3 = 0;
    for (int W = 0; W < NB; W++) {
      fc = lds_poll_ge(&flg[CF + k], W, fc);                 // c staged
      if (k == 0) {
        if (W < 256) fp = lds_poll_ge(&flg[GF], W, fp);      // feed staged
      } else {
        int pn = W + 2; if (pn > 257) pn = 257;              // ring slot W complete
        fp = lds_poll_ge(&flg[PF + k - 1], pn, fp);
      }
      fe = lds_poll_ge(&flg[(k < 3) ? (PF + k + 1) : EF], W - 4, fe);  // ring capacity
      const uint_t* lc = cbuf + (k * 3 + s3) * 1024 + lane;
      uint_t lv[16];
      #pragma unroll
      for (int tp = 0; tp < 16; tp++) lv[tp] = lc[tp * 64];
      float Bv = (k == 0) ? feedb[(W & 3) * 32 + (lane & 31)]
                          : ring[(k - 1) * 128 + (W & 3) * 32 + (lane & 31)];
      float cvv[32];
      #pragma unroll
      for (int tp = 0; tp < 16; tp++) {
        union { uint_t u; _Float16 h[2]; } cu; cu.u = lv[tp];
        cvv[2 * tp]     = (float)cu.h[0];
        cvv[2 * tp + 1] = (float)cu.h[1];
      }
      if (W >= 2 && W < 256) {
        #pragma unroll
        for (int tt = 0; tt < 32; tt++) {
          float Dup = dpp_wave_shr1(Bv, Dcur);
          float m1 = fminf(Dul, Dcur);
          Bv = dpp_wave_rol1(Bv);
          Dcur = cvv[tt] + fminf(m1, Dup);
          Dul = Dup;
          Bout = dpp_wave_shl1(Dcur, Bout);
        }
      } else {
        const int t0 = W * 32;
        #pragma unroll
        for (int tt = 0; tt < 32; tt++) {
          const int t = t0 + tt;
          float Dup = dpp_wave_shr1(Bv, Dcur);
          float m1 = fminf(Dul, Dcur);
          Bv = dpp_wave_rol1(Bv);
          float Dnew = cvv[tt] + fminf(m1, Dup);
          const bool alo = (t >= lane);
          const bool ahi = (t - lane < IL);
          if (alo) Dul = Dup;
          if (alo && ahi) Dcur = Dnew;
          Bout = dpp_wave_shl1(Dcur, Bout);
        }
      }
      if (lane >= 32) {   // verified R8 mapping
        const int slot = (lane == 63) ? (W - 1) : (W - 2);
        if (slot >= 0) ring[k * 128 + ((slot & 3) << 5) + ((lane + 1) & 31)] = Bout;
      }
      __hip_atomic_store(&flg[PF + k], W, __ATOMIC_RELEASE, __HIP_MEMORY_SCOPE_WORKGROUP);
      s3 = (s3 == 2) ? 0 : s3 + 1;
    }
    if (g == 3 && k == 3 && lane == 63) out[0] = Dcur;
  } else if (wv == 4) {
    // ================= c streamer: 1 block/strip/round, depth-2 vmcnt pipeline =================
    // Liveness: during round R, CF[k]=R-2-3k is published, throttle needs PF[k]>=R-3-3k (slack 1).
    int fpk[4] = {-1, -1, -1, -1};
    for (int R = 0; R < NR; R++) {
      const int sl = R % 3;
      #pragma unroll
      for (int k = 0; k < 4; k++) {
        const int B = R - 3 * k;
        const bool v = (B >= 0) && (B < NB);
        if (v) fpk[k] = lds_poll_ge(&flg[PF + k], B - 3, fpk[k]);   // slot-reuse throttle
        const int slot = v ? (k * 3 + sl) : 12;                     // pad -> scratch
        const char* src = (const char*)(c_h + (size_t)(sb + k) * SSH) + (size_t)(v ? B : 0) * 4096;
        uint_t* dst = cbuf + slot * 1024;
        #pragma unroll
        for (int q = 0; q < 4; q++)
          __builtin_amdgcn_global_load_lds(
              (const __attribute__((address_space(1))) void*)(src + (size_t)q * 1024 + lane * 16),
              (__attribute__((address_space(3))) void*)(dst + q * 256 + lane * 4), 16, 0, 0);
      }
      asm volatile("s_waitcnt vmcnt(16)" ::: "memory");   // rounds <= R-1 retired
      #pragma unroll
      for (int k = 0; k < 4; k++) {
        int c = (R - 1) - 3 * k; if (c > 257) c = 257;
        if (c >= 0)
          __hip_atomic_store(&flg[CF + k], c, __ATOMIC_RELAXED, __HIP_MEMORY_SCOPE_WORKGROUP);
      }
    }
    asm volatile("s_waitcnt vmcnt(0)" ::: "memory");
    #pragma unroll
    for (int k = 0; k < 4; k++)
      __hip_atomic_store(&flg[CF + k], 257, __ATOMIC_RELAXED, __HIP_MEMORY_SCOPE_WORKGROUP);
  } else if (wv == 5) {
    // ================= feeder: inbound boundary (g>0), 64 cols per load =================
    if (g > 0) {
      const float* bin = bound + (size_t)(sb - 1) * IL;
      int fg;
      do { fg = __hip_atomic_load(&flags[sb - 1], __ATOMIC_RELAXED, __HIP_MEMORY_SCOPE_AGENT); } while (fg < GATE);
      int fp0 = -1;
      for (int F = 0; F <= 254; F += 2) {
        const int need = 32 * F + 64;
        while (fg < need)
          fg = __hip_atomic_load(&flags[sb - 1], __ATOMIC_RELAXED, __HIP_MEMORY_SCOPE_AGENT);
        float r = __hip_atomic_load(&bin[32 * F + lane], __ATOMIC_RELAXED, __HIP_MEMORY_SCOPE_AGENT);
        fp0 = lds_poll_ge(&flg[PF + 0], F - 3, fp0);         // feed-slot reuse throttle
        feedb[(F & 3) * 32 + lane] = r;                       // fills slots F, F+1
        __hip_atomic_store(&flg[GF], F + 1, __ATOMIC_RELEASE, __HIP_MEMORY_SCOPE_WORKGROUP);
      }
    }
  } else {
    // ================= exporter: wave3 boundary -> global (g<3), depth-3 store pipeline =================
    if (g < 3) {
      float* bout3 = bound + (size_t)(sb + 3) * IL;
      int fp3 = -1;
      for (int E = 0; E < 256; E++) {
        int pn = E + 2; if (pn > 257) pn = 257;
        fp3 = lds_poll_ge(&flg[PF + 3], pn, fp3);             // ring slot E complete
        float bv = ring[3 * 128 + (E & 3) * 32 + (lane & 31)];
        asm volatile("s_waitcnt lgkmcnt(0)" ::: "memory");    // ring read done before eflag
        __hip_atomic_store(&flg[EF], E, __ATOMIC_RELAXED, __HIP_MEMORY_SCOPE_WORKGROUP);
        if (lane < 32)
          __hip_atomic_store(&bout3[32 * E + lane], bv, __ATOMIC_RELAXED, __HIP_MEMORY_SCOPE_AGENT);
        if (E >= 2) {
          asm volatile("s_waitcnt vmcnt(3)" ::: "memory");    // data store E-2 retired
          if (lane == 0)
            __hip_atomic_store(&flags[sb + 3], 32 * (E - 2) + 32, __ATOMIC_RELAXED, __HIP_MEMORY_SCOPE_AGENT);
        }
      }
      asm volatile("s_waitcnt vmcnt(0)" ::: "memory");
      if (lane == 0)
        __hip_atomic_store(&flags[sb + 3], IL, __ATOMIC_RELAXED, __HIP_MEMORY_SCOPE_AGENT);
    }
  }
}

extern "C" void kernel_launch(void* const* d_in, const int* in_sizes, int n_in,
                              void* d_out, int out_size, void* d_ws, size_t ws_size,
                              hipStream_t stream) {
  const float* kern = (const float*)d_in[0]; // (1024,128)
  const float* xx   = (const float*)d_in[1]; // (8192,128)
  char* ws = (char*)d_ws;
  const size_t OFF_X2 = (size_t)NS * SSH * 2;           // c_h: ~16.9 MB
  const size_t OFF_K2 = OFF_X2 + (size_t)IL * 4;
  const size_t OFF_BD = OFF_K2 + (size_t)KL * 4;
  const size_t OFF_FL = OFF_BD + (size_t)NS * IL * 4;
  ushort_t* c_h  = (ushort_t*)ws;
  float* x2    = (float*)(ws + OFF_X2);
  float* k2    = (float*)(ws + OFF_K2);
  float* bnd   = (float*)(ws + OFF_BD);
  int*   flags = (int*)(ws + OFF_FL);

  knorms<<<(IL + KL) / 4, 256, 0, stream>>>(kern, xx, x2, k2, flags);
  kgemm<<<dim3(IL / 64, NS), 256, 0, stream>>>(kern, xx, x2, k2, c_h);
  kdp<<<4, 448, 0, stream>>>(c_h, bnd, flags, (float*)d_out);
}